// Round 11
// baseline (309.589 us; speedup 1.0000x reference)
//
#include <hip/hip_runtime.h>
#include <math.h>
#include <limits.h>

#define N_SAMP 512
#define C_IN   12
#define L_IN   8192
#define NDIL   6
#define NFILT  30
#define NFEAT  180
#define NCHUNK 4
#define CHUNK  (L_IN / NCHUNK)   // 2048
#define EPSV   1e-5f

#define HALO   160               // 5 * max dilation(32)
#define TLC    256               // positions per stage tile
#define LWC    (TLC + 2*HALO)    // 576 rows
#define TILEB  (LWC * 16)        // 9216 bytes per (A|B) part
#define NST    (CHUNK / TLC)     // 8 stages per block

// ws layout: [0, WF_OFF) float partials; then wc, wd (i8 frag tables), bias
#define WF_OFF (3 * N_SAMP * NCHUNK * NFILT * 2)   // 368640 floats
#define WTAB_B (NDIL * 3 * 64 * 16)                // 18432 bytes per table

typedef __attribute__((ext_vector_type(4))) int i32x4;

// XOR swizzle on 16B cells. Key varies under row steps 8,16,32,64,128,256
// (all tap strides d..4d for d=1..32); bijective involution on cell index.
__device__ __forceinline__ int swz(int r) {
    return (r << 4) ^ ((((r >> 3) ^ (r >> 6)) & 7) << 4);
}

// ---------------------------------------------------------------------------
// Build i8 B-fragment tables: W = round(w*8192) = 256*C + D, C in [-32,32],
// D in [-128,127]. MFMA lane layout: k = q*16 + e -> (tap = mf*4+q, c = e).
// tap 11 (mf=2,q=3) is zero-weighted padding.
// ---------------------------------------------------------------------------
__global__ __launch_bounds__(256)
void build_wb(const float* __restrict__ W7, const float* __restrict__ W9,
              const float* __restrict__ W11, const float* __restrict__ b7,
              const float* __restrict__ b9, const float* __restrict__ b11,
              signed char* __restrict__ wc, signed char* __restrict__ wd,
              float* __restrict__ bias_tab)
{
    const int t = blockIdx.x * 256 + threadIdx.x;
    if (t < NDIL * 3 * 64) {
        const int j    = t / 192;
        const int mf   = (t / 64) % 3;
        const int lane = t % 64;
        const int col  = lane & 15;
        const int q    = lane >> 4;
        const int tap  = mf * 4 + q;
#pragma unroll
        for (int e = 0; e < 16; ++e) {
            float v = 0.0f;
            if (col < 15 && tap <= 10 && e < 12) {
                const int toff = tap - 5;
                if (col < 5) {
                    if (toff >= -3 && toff <= 3)
                        v = W7[((j * 5 + col) * 12 + e) * 7 + toff + 3];
                } else if (col < 10) {
                    if (toff >= -4 && toff <= 4)
                        v = W9[((j * 5 + col - 5) * 12 + e) * 9 + toff + 4];
                } else {
                    v = W11[((j * 5 + col - 10) * 12 + e) * 11 + toff + 5];
                }
            }
            const int W  = __float2int_rn(v * 8192.0f);
            const int C8 = (W + 128) >> 8;      // in [-32, 32]
            const int D8 = W - (C8 << 8);       // in [-128, 127]
            wc[(size_t)t * 16 + e] = (signed char)C8;
            wd[(size_t)t * 16 + e] = (signed char)D8;
        }
    } else if (t < NDIL * 3 * 64 + 96) {
        const int i = t - NDIL * 3 * 64;
        const int j = i / 16, s = i % 16;
        float b = 0.0f;
        if (s < 5)       b = b7 [j * 5 + s];
        else if (s < 10) b = b9 [j * 5 + s - 5];
        else if (s < 15) b = b11[j * 5 + s - 10];
        bias_tab[j * 16 + s] = b;
    }
}

// ---------------------------------------------------------------------------
// i8 MFMA conv, EXACT 4-term fixed-point product:
//   X = round(x*4096) = 256A + B;  W = round(w*8192) = 256C + D
//   X*W = 65536*(A.C) + 256*(A.D + B.C) + B.D  (exact in wrapping i32).
// Round-11: DOUBLE-BUFFERED LDS + async stage split (T14/G15):
//   issue global loads for stage st+1 -> regs; compute stage st (LDS+MFMA
//   hides the load latency); quantize+write buf[(st+1)&1]; ONE barrier/stage.
// NOTE: no min-occupancy launch_bounds arg — (256,4) caused 64-VGPR scratch
// spills in rounds 2 and 7. Tripwire for spills here: WRITE_SIZE.
// ---------------------------------------------------------------------------
__global__ __launch_bounds__(256)
void rocket_conv_i8(const float* __restrict__ x,
                    const signed char* __restrict__ wc,
                    const signed char* __restrict__ wd,
                    const float* __restrict__ bias_tab,
                    float* __restrict__ ws)
{
    __shared__ __align__(16) signed char xq[2][2][TILEB];  // [buf][A|B]
    __shared__ int scnt[NDIL * 16];                        // [j][col]
    __shared__ int smx [NDIL * 16];

    const int ch  = blockIdx.x;
    const int n   = blockIdx.y;
    const int tid = threadIdx.x;
    const int lane = tid & 63, wv = tid >> 6;
    const int row_l = lane & 15, q = lane >> 4;
    const float* __restrict__ xrow = x + (size_t)n * C_IN * L_IN;
    const i32x4* __restrict__ wcv = (const i32x4*)wc;
    const i32x4* __restrict__ wdv = (const i32x4*)wd;

    if (tid < NDIL * 16) { scnt[tid] = 0; smx[tid] = INT_MIN; }

    const int c0 = ch * CHUNK;

    // in-flight stage registers: rows tid, tid+256, tid+512 (if < LWC)
    float xv0[12], xv1[12], xv2[12];

#define LOADS(ST)                                                         \
    {                                                                     \
        const int gb = c0 + (ST) * TLC - HALO + tid;                      \
        _Pragma("unroll")                                                 \
        for (int c = 0; c < 12; ++c)                                      \
            xv0[c] = ((unsigned)gb < (unsigned)L_IN)                      \
                         ? xrow[c * L_IN + gb] : 0.0f;                    \
        _Pragma("unroll")                                                 \
        for (int c = 0; c < 12; ++c)                                      \
            xv1[c] = ((unsigned)(gb + 256) < (unsigned)L_IN)              \
                         ? xrow[c * L_IN + gb + 256] : 0.0f;              \
        if (tid < LWC - 512) {                                            \
            _Pragma("unroll")                                             \
            for (int c = 0; c < 12; ++c)                                  \
                xv2[c] = ((unsigned)(gb + 512) < (unsigned)L_IN)          \
                             ? xrow[c * L_IN + gb + 512] : 0.0f;          \
        }                                                                 \
    }

#define QWRITE_ROW(BUF, XV, ROFF)                                        \
    {                                                                    \
        int h[4] = {0, 0, 0, 0}, l[4] = {0, 0, 0, 0};                    \
        _Pragma("unroll")                                                \
        for (int c = 0; c < 12; ++c) {                                   \
            const int X  = __float2int_rn((XV)[c] * 4096.0f);            \
            const int A8 = (X + 128) >> 8;     /* [-91, 91] */           \
            const int B8 = X - (A8 << 8);      /* [-128, 127] */         \
            h[c >> 2] |= (A8 & 255) << ((c & 3) * 8);                    \
            l[c >> 2] |= (B8 & 255) << ((c & 3) * 8);                    \
        }                                                                \
        const int cell_ = swz(tid + (ROFF));                             \
        *(i32x4*)&xq[(BUF)][0][cell_] = (i32x4){h[0], h[1], h[2], h[3]}; \
        *(i32x4*)&xq[(BUF)][1][cell_] = (i32x4){l[0], l[1], l[2], l[3]}; \
    }

#define QWRITE(BUF)                                                      \
    {                                                                    \
        QWRITE_ROW(BUF, xv0, 0)                                          \
        QWRITE_ROW(BUF, xv1, 256)                                        \
        if (tid < LWC - 512) QWRITE_ROW(BUF, xv2, 512)                   \
    }

    // ---- prologue: stage tile 0 into buffer 0 ----
    LOADS(0);
    QWRITE(0);
    __syncthreads();

#pragma unroll 1
    for (int st = 0; st < NST; ++st) {
        // issue next stage's global loads (in flight under compute)
        if (st + 1 < NST) LOADS(st + 1);

        const signed char* __restrict__ xa = &xq[st & 1][0][0];
        const signed char* __restrict__ xb = &xq[st & 1][1][0];

        // ---- compute: dilations ROLLED, 4 pos-tiles/wave each ----
#pragma unroll 1
        for (int j = 0; j < NDIL; ++j) {
            const int d = 1 << j;
            const i32x4 C0 = wcv[(j * 3 + 0) * 64 + lane];
            const i32x4 C1 = wcv[(j * 3 + 1) * 64 + lane];
            const i32x4 C2 = wcv[(j * 3 + 2) * 64 + lane];
            const i32x4 D0 = wdv[(j * 3 + 0) * 64 + lane];
            const i32x4 D1 = wdv[(j * 3 + 1) * 64 + lane];
            const i32x4 D2 = wdv[(j * 3 + 2) * 64 + lane];
            // integer threshold: out>0  <=>  tot > -bias*2^25
            const float bj = bias_tab[j * 16 + row_l];
            const int tj = (int)floorf(bj * -33554432.0f);
            // per-lane A row offsets for taps {q, q+4, q+8} (tap 11 -> 0)
            const int r0 = HALO + wv * 64 + row_l + (q - 5) * d;
            const int r1 = HALO + wv * 64 + row_l + (q - 1) * d;
            const int r2 = HALO + wv * 64 + row_l +
                           ((q == 3) ? 0 : (q + 3) * d);

            int cnt_i = 0, mx_i = INT_MIN;
#pragma unroll
            for (int t = 0; t < 4; ++t) {
                const int cell0 = swz(r0 + 16 * t);
                const int cell1 = swz(r1 + 16 * t);
                const int cell2 = swz(r2 + 16 * t);
                i32x4 a0 = {0, 0, 0, 0};   // A.C
                i32x4 a1 = {0, 0, 0, 0};   // A.D + B.C
                i32x4 a2 = {0, 0, 0, 0};   // B.D
                {
                    i32x4 ah = *(const i32x4*)&xa[cell0];
                    i32x4 al = *(const i32x4*)&xb[cell0];
                    a0 = __builtin_amdgcn_mfma_i32_16x16x64_i8(ah, C0, a0, 0, 0, 0);
                    a1 = __builtin_amdgcn_mfma_i32_16x16x64_i8(ah, D0, a1, 0, 0, 0);
                    a1 = __builtin_amdgcn_mfma_i32_16x16x64_i8(al, C0, a1, 0, 0, 0);
                    a2 = __builtin_amdgcn_mfma_i32_16x16x64_i8(al, D0, a2, 0, 0, 0);
                }
                {
                    i32x4 ah = *(const i32x4*)&xa[cell1];
                    i32x4 al = *(const i32x4*)&xb[cell1];
                    a0 = __builtin_amdgcn_mfma_i32_16x16x64_i8(ah, C1, a0, 0, 0, 0);
                    a1 = __builtin_amdgcn_mfma_i32_16x16x64_i8(ah, D1, a1, 0, 0, 0);
                    a1 = __builtin_amdgcn_mfma_i32_16x16x64_i8(al, C1, a1, 0, 0, 0);
                    a2 = __builtin_amdgcn_mfma_i32_16x16x64_i8(al, D1, a2, 0, 0, 0);
                }
                {
                    i32x4 ah = *(const i32x4*)&xa[cell2];
                    i32x4 al = *(const i32x4*)&xb[cell2];
                    a0 = __builtin_amdgcn_mfma_i32_16x16x64_i8(ah, C2, a0, 0, 0, 0);
                    a1 = __builtin_amdgcn_mfma_i32_16x16x64_i8(ah, D2, a1, 0, 0, 0);
                    a1 = __builtin_amdgcn_mfma_i32_16x16x64_i8(al, C2, a1, 0, 0, 0);
                    a2 = __builtin_amdgcn_mfma_i32_16x16x64_i8(al, D2, a2, 0, 0, 0);
                }
                int t01, t23;
                {
                    const int v0 = (a0[0] << 16) + (a1[0] << 8) + a2[0];
                    const int v1 = (a0[1] << 16) + (a1[1] << 8) + a2[1];
                    const int v2 = (a0[2] << 16) + (a1[2] << 8) + a2[2];
                    const int v3 = (a0[3] << 16) + (a1[3] << 8) + a2[3];
                    cnt_i += (v0 > tj) + (v1 > tj) + (v2 > tj) + (v3 > tj);
                    t01 = (v0 > v1) ? v0 : v1;
                    t23 = (v2 > v3) ? v2 : v3;
                }
                const int tmx = (t01 > t23) ? t01 : t23;
                mx_i = (tmx > mx_i) ? tmx : mx_i;
            }

            // flush this dilation's stats (block-shared, LDS atomics)
            cnt_i += __shfl_xor(cnt_i, 16);
            cnt_i += __shfl_xor(cnt_i, 32);
            {
                int o = __shfl_xor(mx_i, 16);  mx_i = (o > mx_i) ? o : mx_i;
                o     = __shfl_xor(mx_i, 32);  mx_i = (o > mx_i) ? o : mx_i;
            }
            if (lane < 16) {
                atomicAdd(&scnt[j * 16 + lane], cnt_i);
                atomicMax(&smx[j * 16 + lane], mx_i);
            }
        }

        // write next tile into the other buffer (readers use buf[st&1])
        if (st + 1 < NST) QWRITE((st + 1) & 1);
        __syncthreads();
    }

    if (tid < 96) {
        const int jj = tid >> 4, s = tid & 15;
        if (s < 15) {
            const int c = scnt[jj * 16 + s];
            const int m = smx[jj * 16 + s];
            const float bj = bias_tab[jj * 16 + s];
            const int ks = s / 5, f = s % 5;
            const int gg = jj * 5 + f;
            const size_t base =
                ((((size_t)ks * N_SAMP + n) * NCHUNK + ch) * NFILT + gg) * 2;
            ws[base]     = (float)c;
            ws[base + 1] = bj + (float)m * 2.9802322387695312e-8f; // 2^-25
        }
    }
#undef LOADS
#undef QWRITE_ROW
#undef QWRITE
}

// ---------------------------------------------------------------------------
// Reduce chunks -> feature value, then per-feature batch norm.
// ---------------------------------------------------------------------------
__global__ __launch_bounds__(512)
void rocket_finish(const float* __restrict__ ws, float* __restrict__ out)
{
    const int i = blockIdx.x;
    const int t = threadIdx.x;

    const int ks = i / 60;
    const int r  = i % 60;
    const int g  = r >> 1;
    const int m  = r & 1;

    const size_t base =
        ((((size_t)ks * N_SAMP + t) * NCHUNK) * NFILT + g) * 2 + m;

    float v;
    if (m) {
        v = -INFINITY;
#pragma unroll
        for (int c = 0; c < NCHUNK; ++c)
            v = fmaxf(v, ws[base + (size_t)c * NFILT * 2]);
    } else {
        v = 0.0f;
#pragma unroll
        for (int c = 0; c < NCHUNK; ++c)
            v += ws[base + (size_t)c * NFILT * 2];
        v *= (1.0f / (float)L_IN);
    }

    float s  = v;
    float sq = v * v;
#pragma unroll
    for (int off = 32; off; off >>= 1) {
        s  += __shfl_xor(s, off);
        sq += __shfl_xor(sq, off);
    }

    __shared__ float ss[8], sqq[8];
    const int lane = t & 63;
    const int wv   = t >> 6;
    if (lane == 0) { ss[wv] = s; sqq[wv] = sq; }
    __syncthreads();
    if (t == 0) {
        float S = 0.0f, Q = 0.0f;
#pragma unroll
        for (int w = 0; w < 8; ++w) { S += ss[w]; Q += sqq[w]; }
        ss[0] = S; sqq[0] = Q;
    }
    __syncthreads();

    const float mean = ss[0] * (1.0f / (float)N_SAMP);
    const float var  = sqq[0] * (1.0f / (float)N_SAMP) - mean * mean;
    out[t * NFEAT + i] = (v - mean) / sqrtf(var + EPSV);
}

// ---------------------------------------------------------------------------
extern "C" void kernel_launch(void* const* d_in, const int* in_sizes, int n_in,
                              void* d_out, int out_size, void* d_ws, size_t ws_size,
                              hipStream_t stream)
{
    const float* x   = (const float*)d_in[0];
    const float* W7  = (const float*)d_in[1];
    const float* b7  = (const float*)d_in[2];
    const float* W9  = (const float*)d_in[3];
    const float* b9  = (const float*)d_in[4];
    const float* W11 = (const float*)d_in[5];
    const float* b11 = (const float*)d_in[6];
    float* out = (float*)d_out;
    float* ws  = (float*)d_ws;                 // 1.47 MB partials + tables
    signed char* wc = (signed char*)(ws + WF_OFF);
    signed char* wd = wc + WTAB_B;
    float* bias_tab = (float*)(wd + WTAB_B);

    build_wb<<<5, 256, 0, stream>>>(W7, W9, W11, b7, b9, b11, wc, wd, bias_tab);

    dim3 grid(NCHUNK, N_SAMP);
    rocket_conv_i8<<<grid, 256, 0, stream>>>(x, wc, wd, bias_tab, ws);

    rocket_finish<<<NFEAT, 512, 0, stream>>>(ws, out);
}

// Round 12
// 273.196 us; speedup vs baseline: 1.1332x; 1.1332x over previous
//
#include <hip/hip_runtime.h>
#include <math.h>
#include <limits.h>

#define N_SAMP 512
#define C_IN   12
#define L_IN   8192
#define NDIL   6
#define NFILT  30
#define NFEAT  180
#define NCHUNK 4
#define CHUNK  (L_IN / NCHUNK)   // 2048
#define EPSV   1e-5f

#define HALO   160               // 5 * max dilation(32)
#define TLC    1024              // positions per stage tile (round-12: big)
#define LWC    (TLC + 2*HALO)    // 1344 rows
#define TILEB  (LWC * 16)        // 21504 bytes per (A|B) part
#define NST    (CHUNK / TLC)     // 2 stages per block

// ws layout: [0, WF_OFF) float partials; then wc, wd (i8 frag tables), bias
#define WF_OFF (3 * N_SAMP * NCHUNK * NFILT * 2)   // 368640 floats
#define WTAB_B (NDIL * 3 * 64 * 16)                // 18432 bytes per table

typedef __attribute__((ext_vector_type(4))) int i32x4;

// XOR swizzle on 16B cells. Key varies under row steps 8,16,32,64,128,256
// (all tap strides d..4d for d=1..32); bijective involution on cell index.
__device__ __forceinline__ int swz(int r) {
    return (r << 4) ^ ((((r >> 3) ^ (r >> 6)) & 7) << 4);
}

__device__ __forceinline__ int imax(int a, int b) { return a > b ? a : b; }

// ---------------------------------------------------------------------------
// Build i8 B-fragment tables: W = round(w*8192) = 256*C + D, C in [-32,32],
// D in [-128,127]. MFMA lane layout: k = q*16 + e -> (tap = mf*4+q, c = e).
// tap 11 (mf=2,q=3) is zero-weighted padding.
// ---------------------------------------------------------------------------
__global__ __launch_bounds__(256)
void build_wb(const float* __restrict__ W7, const float* __restrict__ W9,
              const float* __restrict__ W11, const float* __restrict__ b7,
              const float* __restrict__ b9, const float* __restrict__ b11,
              signed char* __restrict__ wc, signed char* __restrict__ wd,
              float* __restrict__ bias_tab)
{
    const int t = blockIdx.x * 256 + threadIdx.x;
    if (t < NDIL * 3 * 64) {
        const int j    = t / 192;
        const int mf   = (t / 64) % 3;
        const int lane = t % 64;
        const int col  = lane & 15;
        const int q    = lane >> 4;
        const int tap  = mf * 4 + q;
#pragma unroll
        for (int e = 0; e < 16; ++e) {
            float v = 0.0f;
            if (col < 15 && tap <= 10 && e < 12) {
                const int toff = tap - 5;
                if (col < 5) {
                    if (toff >= -3 && toff <= 3)
                        v = W7[((j * 5 + col) * 12 + e) * 7 + toff + 3];
                } else if (col < 10) {
                    if (toff >= -4 && toff <= 4)
                        v = W9[((j * 5 + col - 5) * 12 + e) * 9 + toff + 4];
                } else {
                    v = W11[((j * 5 + col - 10) * 12 + e) * 11 + toff + 5];
                }
            }
            const int W  = __float2int_rn(v * 8192.0f);
            const int C8 = (W + 128) >> 8;      // in [-32, 32]
            const int D8 = W - (C8 << 8);       // in [-128, 127]
            wc[(size_t)t * 16 + e] = (signed char)C8;
            wd[(size_t)t * 16 + e] = (signed char)D8;
        }
    } else if (t < NDIL * 3 * 64 + 96) {
        const int i = t - NDIL * 3 * 64;
        const int j = i / 16, s = i % 16;
        float b = 0.0f;
        if (s < 5)       b = b7 [j * 5 + s];
        else if (s < 10) b = b9 [j * 5 + s - 5];
        else if (s < 15) b = b11[j * 5 + s - 10];
        bias_tab[j * 16 + s] = b;
    }
}

// ---------------------------------------------------------------------------
// i8 MFMA conv, EXACT 4-term fixed-point product:
//   X = round(x*4096) = 256A + B;  W = round(w*8192) = 256C + D
//   X*W = 65536*(A.C) + 256*(A.D + B.C) + B.D  (exact in wrapping i32).
// Round-12: TLC=1024 (43.8 KB LDS, 3 blocks/CU — matches the ~3-block
// residency plateau measured in rounds 9-11 regardless of LDS), 2 stages,
// 4 barriers/block, single-buffered (round-9 schedule, empirically best).
// NOTE: no min-occupancy launch_bounds arg — (256,4) caused 64-VGPR scratch
// spills in rounds 2 and 7.
// ---------------------------------------------------------------------------
__global__ __launch_bounds__(256)
void rocket_conv_i8(const float* __restrict__ x,
                    const signed char* __restrict__ wc,
                    const signed char* __restrict__ wd,
                    const float* __restrict__ bias_tab,
                    float* __restrict__ ws)
{
    __shared__ __align__(16) signed char xq[2][TILEB];   // A | B, 43008 B
    __shared__ int scnt[NDIL * 16];                      // [j][col]
    __shared__ int smx [NDIL * 16];

    const int ch  = blockIdx.x;
    const int n   = blockIdx.y;
    const int tid = threadIdx.x;
    const int lane = tid & 63, wv = tid >> 6;
    const int row_l = lane & 15, q = lane >> 4;
    const float* __restrict__ xrow = x + (size_t)n * C_IN * L_IN;
    const i32x4* __restrict__ wcv = (const i32x4*)wc;
    const i32x4* __restrict__ wdv = (const i32x4*)wd;

    if (tid < NDIL * 16) { scnt[tid] = 0; smx[tid] = INT_MIN; }

    const int c0 = ch * CHUNK;
#pragma unroll 1
    for (int st = 0; st < NST; ++st) {
        const int t0 = c0 + st * TLC;
        __syncthreads();   // covers stats init on st==0, xq reuse after
        // ---- stage: quantize x to (A,B) i8 pairs, swizzled 16B rows ----
#pragma unroll 1
        for (int r = tid; r < LWC; r += 256) {
            const int g = t0 - HALO + r;
            int h[4] = {0, 0, 0, 0}, l[4] = {0, 0, 0, 0};
            if ((unsigned)g < (unsigned)L_IN) {
#pragma unroll
                for (int c = 0; c < 12; ++c) {
                    const float xv = xrow[c * L_IN + g];
                    const int X  = __float2int_rn(xv * 4096.0f);
                    const int A8 = (X + 128) >> 8;     // [-91, 91]
                    const int B8 = X - (A8 << 8);      // [-128, 127]
                    h[c >> 2] |= (A8 & 255) << ((c & 3) * 8);
                    l[c >> 2] |= (B8 & 255) << ((c & 3) * 8);
                }
            }
            const int cell = swz(r);
            *(i32x4*)&xq[0][cell] = (i32x4){h[0], h[1], h[2], h[3]};
            *(i32x4*)&xq[1][cell] = (i32x4){l[0], l[1], l[2], l[3]};
        }
        __syncthreads();

        // ---- compute: dilations ROLLED, 16 pos-tiles/wave each ----
#pragma unroll 1
        for (int j = 0; j < NDIL; ++j) {
            const int d = 1 << j;
            const i32x4 C0 = wcv[(j * 3 + 0) * 64 + lane];
            const i32x4 C1 = wcv[(j * 3 + 1) * 64 + lane];
            const i32x4 C2 = wcv[(j * 3 + 2) * 64 + lane];
            const i32x4 D0 = wdv[(j * 3 + 0) * 64 + lane];
            const i32x4 D1 = wdv[(j * 3 + 1) * 64 + lane];
            const i32x4 D2 = wdv[(j * 3 + 2) * 64 + lane];
            // integer threshold: out>0  <=>  tot > -bias*2^25
            const float bj = bias_tab[j * 16 + row_l];
            const int tj = (int)floorf(bj * -33554432.0f);
            // per-lane A row offsets for taps {q, q+4, q+8} (tap 11 -> 0)
            const int r0 = HALO + wv * 256 + row_l + (q - 5) * d;
            const int r1 = HALO + wv * 256 + row_l + (q - 1) * d;
            const int r2 = HALO + wv * 256 + row_l +
                           ((q == 3) ? 0 : (q + 3) * d);

            int cnt_i = 0, mx_i = INT_MIN;
#pragma unroll 4
            for (int t = 0; t < 16; ++t) {
                const int cell0 = swz(r0 + 16 * t);
                const int cell1 = swz(r1 + 16 * t);
                const int cell2 = swz(r2 + 16 * t);
                i32x4 a0 = {0, 0, 0, 0};   // A.C
                i32x4 a1 = {0, 0, 0, 0};   // A.D + B.C
                i32x4 a2 = {0, 0, 0, 0};   // B.D
                {
                    i32x4 ah = *(const i32x4*)&xq[0][cell0];
                    i32x4 al = *(const i32x4*)&xq[1][cell0];
                    a0 = __builtin_amdgcn_mfma_i32_16x16x64_i8(ah, C0, a0, 0, 0, 0);
                    a1 = __builtin_amdgcn_mfma_i32_16x16x64_i8(ah, D0, a1, 0, 0, 0);
                    a1 = __builtin_amdgcn_mfma_i32_16x16x64_i8(al, C0, a1, 0, 0, 0);
                    a2 = __builtin_amdgcn_mfma_i32_16x16x64_i8(al, D0, a2, 0, 0, 0);
                }
                {
                    i32x4 ah = *(const i32x4*)&xq[0][cell1];
                    i32x4 al = *(const i32x4*)&xq[1][cell1];
                    a0 = __builtin_amdgcn_mfma_i32_16x16x64_i8(ah, C1, a0, 0, 0, 0);
                    a1 = __builtin_amdgcn_mfma_i32_16x16x64_i8(ah, D1, a1, 0, 0, 0);
                    a1 = __builtin_amdgcn_mfma_i32_16x16x64_i8(al, C1, a1, 0, 0, 0);
                    a2 = __builtin_amdgcn_mfma_i32_16x16x64_i8(al, D1, a2, 0, 0, 0);
                }
                {
                    i32x4 ah = *(const i32x4*)&xq[0][cell2];
                    i32x4 al = *(const i32x4*)&xq[1][cell2];
                    a0 = __builtin_amdgcn_mfma_i32_16x16x64_i8(ah, C2, a0, 0, 0, 0);
                    a1 = __builtin_amdgcn_mfma_i32_16x16x64_i8(ah, D2, a1, 0, 0, 0);
                    a1 = __builtin_amdgcn_mfma_i32_16x16x64_i8(al, C2, a1, 0, 0, 0);
                    a2 = __builtin_amdgcn_mfma_i32_16x16x64_i8(al, D2, a2, 0, 0, 0);
                }
                // tot = (a0<<16) + (a1<<8) + a2 : two v_lshl_add each
                const int v0 = ((a0[0] << 8) + a1[0] << 8) + a2[0];
                const int v1 = ((a0[1] << 8) + a1[1] << 8) + a2[1];
                const int v2 = ((a0[2] << 8) + a1[2] << 8) + a2[2];
                const int v3 = ((a0[3] << 8) + a1[3] << 8) + a2[3];
                cnt_i += (v0 > tj) + (v1 > tj) + (v2 > tj) + (v3 > tj);
                mx_i = imax(mx_i, imax(imax(v0, v1), imax(v2, v3)));
            }

            // flush this dilation's stats (block-shared, LDS atomics)
            cnt_i += __shfl_xor(cnt_i, 16);
            cnt_i += __shfl_xor(cnt_i, 32);
            mx_i = imax(mx_i, __shfl_xor(mx_i, 16));
            mx_i = imax(mx_i, __shfl_xor(mx_i, 32));
            if (lane < 16) {
                atomicAdd(&scnt[j * 16 + lane], cnt_i);
                atomicMax(&smx[j * 16 + lane], mx_i);
            }
        }
    }

    __syncthreads();
    if (tid < 96) {
        const int jj = tid >> 4, s = tid & 15;
        if (s < 15) {
            const int c = scnt[jj * 16 + s];
            const int m = smx[jj * 16 + s];
            const float bj = bias_tab[jj * 16 + s];
            const int ks = s / 5, f = s % 5;
            const int gg = jj * 5 + f;
            const size_t base =
                ((((size_t)ks * N_SAMP + n) * NCHUNK + ch) * NFILT + gg) * 2;
            ws[base]     = (float)c;
            ws[base + 1] = bj + (float)m * 2.9802322387695312e-8f; // 2^-25
        }
    }
}

// ---------------------------------------------------------------------------
// Reduce chunks -> feature value, then per-feature batch norm.
// ---------------------------------------------------------------------------
__global__ __launch_bounds__(512)
void rocket_finish(const float* __restrict__ ws, float* __restrict__ out)
{
    const int i = blockIdx.x;
    const int t = threadIdx.x;

    const int ks = i / 60;
    const int r  = i % 60;
    const int g  = r >> 1;
    const int m  = r & 1;

    const size_t base =
        ((((size_t)ks * N_SAMP + t) * NCHUNK) * NFILT + g) * 2 + m;

    float v;
    if (m) {
        v = -INFINITY;
#pragma unroll
        for (int c = 0; c < NCHUNK; ++c)
            v = fmaxf(v, ws[base + (size_t)c * NFILT * 2]);
    } else {
        v = 0.0f;
#pragma unroll
        for (int c = 0; c < NCHUNK; ++c)
            v += ws[base + (size_t)c * NFILT * 2];
        v *= (1.0f / (float)L_IN);
    }

    float s  = v;
    float sq = v * v;
#pragma unroll
    for (int off = 32; off; off >>= 1) {
        s  += __shfl_xor(s, off);
        sq += __shfl_xor(sq, off);
    }

    __shared__ float ss[8], sqq[8];
    const int lane = t & 63;
    const int wv   = t >> 6;
    if (lane == 0) { ss[wv] = s; sqq[wv] = sq; }
    __syncthreads();
    if (t == 0) {
        float S = 0.0f, Q = 0.0f;
#pragma unroll
        for (int w = 0; w < 8; ++w) { S += ss[w]; Q += sqq[w]; }
        ss[0] = S; sqq[0] = Q;
    }
    __syncthreads();

    const float mean = ss[0] * (1.0f / (float)N_SAMP);
    const float var  = sqq[0] * (1.0f / (float)N_SAMP) - mean * mean;
    out[t * NFEAT + i] = (v - mean) / sqrtf(var + EPSV);
}

// ---------------------------------------------------------------------------
extern "C" void kernel_launch(void* const* d_in, const int* in_sizes, int n_in,
                              void* d_out, int out_size, void* d_ws, size_t ws_size,
                              hipStream_t stream)
{
    const float* x   = (const float*)d_in[0];
    const float* W7  = (const float*)d_in[1];
    const float* b7  = (const float*)d_in[2];
    const float* W9  = (const float*)d_in[3];
    const float* b9  = (const float*)d_in[4];
    const float* W11 = (const float*)d_in[5];
    const float* b11 = (const float*)d_in[6];
    float* out = (float*)d_out;
    float* ws  = (float*)d_ws;                 // 1.47 MB partials + tables
    signed char* wc = (signed char*)(ws + WF_OFF);
    signed char* wd = wc + WTAB_B;
    float* bias_tab = (float*)(wd + WTAB_B);

    build_wb<<<5, 256, 0, stream>>>(W7, W9, W11, b7, b9, b11, wc, wd, bias_tab);

    dim3 grid(NCHUNK, N_SAMP);
    rocket_conv_i8<<<grid, 256, 0, stream>>>(x, wc, wd, bias_tab, ws);

    rocket_finish<<<NFEAT, 512, 0, stream>>>(ws, out);
}